// Round 6
// baseline (452.580 us; speedup 1.0000x reference)
//
#include <hip/hip_runtime.h>
#include <hip/hip_bf16.h>

// ---------------------------------------------------------------------------
// GraphSAGE 3-layer, bf16, bucket-CSR. R16 = R15 EXACTLY, except each
// aggregate_mean_bf16 is launched TWICE (idempotent: recomputes identical
// mean from unchanged wptr/bkt). ATTRIBUTION PROBE:
//   total - 382.5 = aggregation total cost (warm-biased lower bound);
//   if agg0 >= ~61us it surfaces above the 60us fillBuffer rows in top-5,
//   yielding its true duration + regime counters.
// R14/R15 lesson: two GEMM restructures moved total <2% — the ~310us
// non-fill budget is unmeasured; stop gambling, measure.
// ---------------------------------------------------------------------------

typedef __attribute__((ext_vector_type(8))) short bf16x8;
typedef __attribute__((ext_vector_type(8))) unsigned short u16x8;
typedef __attribute__((ext_vector_type(4))) float floatx4;

constexpr int M0 = 50000, M1 = 25000, M2 = 12500;
constexpr int NODE_OFF1 = 50000, NODE_OFF2 = 75000, M_TOT = 87500;
constexpr int NSRC = 100000;
constexpr int NPART = 8;
constexpr int CAP = 64;     // bucket capacity per node

__device__ inline unsigned short f2bf(float f) {
    union { float f; unsigned int u; } v{f};
    unsigned int u = v.u;
    return (unsigned short)((u + 0x7FFFu + ((u >> 16) & 1u)) >> 16);  // RNE
}
__device__ inline float bf2f(unsigned short h) {
    union { unsigned int u; float f; } v{(unsigned int)h << 16};
    return v.f;
}

__device__ inline void gload_lds16(const void* g, void* l) {
    __builtin_amdgcn_global_load_lds(
        (const __attribute__((address_space(1))) unsigned int*)g,
        (__attribute__((address_space(3))) unsigned int*)l, 16, 0, 0);
}

// ---- cast + weight prep ---------------------------------------------------
constexpr int CAST_B = 25000;           // NSRC*256/4 / 256
constexpr int PREP_B = 640;

__global__ __launch_bounds__(256) void cast_prep_kernel(
    const float* __restrict__ x, unsigned short* __restrict__ xb,
    const float* __restrict__ Wn0, const float* __restrict__ Ws0,
    const float* __restrict__ Wn1, const float* __restrict__ Ws1,
    const float* __restrict__ Wn2, const float* __restrict__ Ws2,
    unsigned short* __restrict__ Wt0, unsigned short* __restrict__ Wt1,
    unsigned short* __restrict__ Wt2)
{
    const int blk = blockIdx.x;
    if (blk < CAST_B) {
        long i = (long)blk * 256 + threadIdx.x;     // over NSRC*64 ushort4's
        float4 v = reinterpret_cast<const float4*>(x)[i];
        ushort4 o{f2bf(v.x), f2bf(v.y), f2bf(v.z), f2bf(v.w)};
        reinterpret_cast<ushort4*>(xb)[i] = o;
    } else {
        int b = blk - CAST_B;
        const float* Wn; const float* Ws; unsigned short* Wt; int N; int base;
        if (b < 256)      { Wn = Wn0; Ws = Ws0; Wt = Wt0; N = 256; base = 0; }
        else if (b < 512) { Wn = Wn1; Ws = Ws1; Wt = Wt1; N = 256; base = 256; }
        else              { Wn = Wn2; Ws = Ws2; Wt = Wt2; N = 128; base = 512; }
        int idx = (b - base) * 256 + threadIdx.x;   // over N*256, k fastest
        int n = idx >> 8, k = idx & 255;
        if (n >= N) return;
        Wt[(size_t)n * 512 + k]       = f2bf(Wn[(size_t)k * N + n]);
        Wt[(size_t)n * 512 + 256 + k] = f2bf(Ws[(size_t)k * N + n]);
    }
}

// ---- bucket scatter -------------------------------------------------------
// node-partitioned: b&7 = node partition (contiguous node range -> XCD-local
// bkt store lines), b>>3 = edge slice. src[] read only on commit (1/8).
__global__ __launch_bounds__(256) void scatter_kernel(
    const int* __restrict__ src0, const int* __restrict__ dst0,
    const int* __restrict__ src1, const int* __restrict__ dst1,
    const int* __restrict__ src2, const int* __restrict__ dst2,
    int* __restrict__ wptr, int* __restrict__ bkt,
    int E0, int E1, int E2)
{
    const int b = blockIdx.x;
    const int part = b & (NPART - 1);
    const int i = (b >> 3) * 256 + threadIdx.x;
    const int lo = (int)(((long)M_TOT * part) / NPART);
    const int hi = (int)(((long)M_TOT * (part + 1)) / NPART);
    int node, j;
    const int* sp;
    if (i < E0) {
        node = dst0[i]; sp = src0; j = i;
    } else if (i < E0 + E1) {
        j = i - E0; node = NODE_OFF1 + dst1[j]; sp = src1;
    } else if (i < E0 + E1 + E2) {
        j = i - E0 - E1; node = NODE_OFF2 + dst2[j]; sp = src2;
    } else return;
    if (node >= lo && node < hi) {
        int s = sp[j];
        int p = atomicAdd(&wptr[node], 1);
        if (p < CAP) bkt[(size_t)node * CAP + p] = s;
    }
}

// ---- Aggregation: 1 wave/node, 2 rows per iteration (16B/lane) ------------

__global__ __launch_bounds__(256) void aggregate_mean_bf16(
    const unsigned short* __restrict__ h, const int* __restrict__ wptr,
    const int* __restrict__ bkt, unsigned short* __restrict__ mean, int M)
{
    int gid = blockIdx.x * 256 + threadIdx.x;
    int node = gid >> 6;
    int lane = gid & 63;
    if (node >= M) return;
    int cnt = min(wptr[node], CAP);
    int sidx = bkt[(size_t)node * CAP + lane];      // whole list, 1 coalesced read
    const int half = lane >> 5;
    const int lq = lane & 31;
    const unsigned short* hb = h + lq * 8;
    float acc[8] = {};
    int pf = cnt >> 1;          // full pairs: both halves valid, no predication
    int p = 0;
    for (; p + 4 <= pf; p += 4) {
#pragma unroll
        for (int j = 0; j < 4; ++j) {
            int s = __shfl(sidx, 2 * (p + j) + half);
            u16x8 row = *(const u16x8*)(hb + (size_t)s * 256);
#pragma unroll
            for (int k = 0; k < 8; ++k) acc[k] += bf2f(row[k]);
        }
    }
    for (; p < pf; ++p) {
        int s = __shfl(sidx, 2 * p + half);
        u16x8 row = *(const u16x8*)(hb + (size_t)s * 256);
#pragma unroll
        for (int k = 0; k < 8; ++k) acc[k] += bf2f(row[k]);
    }
    if (cnt & 1) {              // odd tail: even half only
        int s = __shfl(sidx, cnt - 1);
        if (half == 0) {
            u16x8 row = *(const u16x8*)(hb + (size_t)s * 256);
#pragma unroll
            for (int k = 0; k < 8; ++k) acc[k] += bf2f(row[k]);
        }
    }
#pragma unroll
    for (int k = 0; k < 8; ++k) acc[k] += __shfl_xor(acc[k], 32);
    if (half == 0) {
        float invd = 1.0f / (float)max(cnt, 1);
        u16x8 o;
#pragma unroll
        for (int k = 0; k < 8; ++k) o[k] = f2bf(acc[k] * invd);
        *(u16x8*)(mean + (size_t)node * 256 + lq * 8) = o;
    }
}

// ---- Fused-K MFMA GEMM, 2-phase double-buffered ---------------------------
// C[m][n] = sum_{k<512} Acat[m][k] * Wt[n][k],  Acat = [mean | h] (K-concat).
// 128x128 tile, BK=64, 4 waves, 64x64/wave as 4x4 mfma_f32_16x16x32_bf16.
// Staging: global_load_lds 16B; LDS linear, XOR-swizzle pair (rule #21).
// Schedule: T3 2-phase — STAGE(next) || compute(cur), vmcnt(0)+s_barrier
// once per K-step.

template <int RELU, int OUT_BF16>
__global__ __launch_bounds__(256) void sage_mfma(
    const unsigned short* __restrict__ A1,  // mean  [>=ceil128(M)][256]
    const unsigned short* __restrict__ A2,  // hsrc  [>=ceil128(M)][256]
    const unsigned short* __restrict__ Wt,  // [N][512]
    const float* __restrict__ bias,
    void* __restrict__ out, int M, int N)
{
    __shared__ unsigned short sA[2][128 * 64];   // 2 x 16 KB
    __shared__ unsigned short sB[2][128 * 64];   // 2 x 16 KB

    const int tid = threadIdx.x;
    const int bm = blockIdx.y * 128;
    const int bn = blockIdx.x * 128;
    const int wid = tid >> 6, lane = tid & 63;
    const int wm = (wid >> 1) * 64;
    const int wn = (wid & 1) * 64;
    const int quad = lane >> 4, l16 = lane & 15;

    const int srow = lane >> 3;
    const int swz = ((lane & 7) * 16) ^ (srow << 4);
    const int rswz = (l16 & 7) << 4;

    floatx4 acc[4][4] = {};

    auto stage = [&](int buf, int t) {
        const int k0 = t * 64;
        const unsigned short* Ab = (k0 < 256) ? A1 : A2;
        const int ak = k0 & 255;
#pragma unroll
        for (int u = 0; u < 4; ++u) {
            const int g = wid * 4 + u;            // 0..15, 8 rows each
            const int r = g * 8 + srow;
            gload_lds16((const char*)(Ab + (size_t)(bm + r) * 256 + ak) + swz,
                        (char*)(sA[buf]) + g * 1024);
            gload_lds16((const char*)(Wt + (size_t)(bn + r) * 512 + k0) + swz,
                        (char*)(sB[buf]) + g * 1024);
        }
    };

    auto compute = [&](int buf) {
#pragma unroll
        for (int ks = 0; ks < 64; ks += 32) {
            bf16x8 af[4], bfr[4];
#pragma unroll
            for (int i = 0; i < 4; ++i) {
                const int row = wm + i * 16 + l16;
                af[i] = *(const bf16x8*)((const char*)(sA[buf]) + row * 128 +
                                         ((ks * 2 + quad * 16) ^ rswz));
            }
#pragma unroll
            for (int j = 0; j < 4; ++j) {
                const int row = wn + j * 16 + l16;
                bfr[j] = *(const bf16x8*)((const char*)(sB[buf]) + row * 128 +
                                          ((ks * 2 + quad * 16) ^ rswz));
            }
#pragma unroll
            for (int i = 0; i < 4; ++i)
#pragma unroll
                for (int j = 0; j < 4; ++j)
                    acc[i][j] = __builtin_amdgcn_mfma_f32_16x16x32_bf16(
                        af[i], bfr[j], acc[i][j], 0, 0, 0);
        }
    };

    // prologue
    stage(0, 0);
    asm volatile("s_waitcnt vmcnt(0)" ::: "memory");
    __builtin_amdgcn_s_barrier();

#pragma unroll
    for (int t = 0; t < 8; ++t) {
        const int cur = t & 1;
        if (t < 7) stage(cur ^ 1, t + 1);   // issue next-tile loads first
        compute(cur);                        // ds_read + MFMA on current
        if (t < 7) {
            asm volatile("s_waitcnt vmcnt(0)" ::: "memory");
            __builtin_amdgcn_s_barrier();
        }
    }

    // epilogue: C row = quad*4 + reg, col = l16 (verified m89/m91)
#pragma unroll
    for (int j = 0; j < 4; ++j) {
        int col = bn + wn + j * 16 + l16;
        float bcol = bias[col];
#pragma unroll
        for (int i = 0; i < 4; ++i) {
#pragma unroll
            for (int r = 0; r < 4; ++r) {
                int row = bm + wm + i * 16 + quad * 4 + r;
                if (row < M) {
                    float v = acc[i][j][r] + bcol;
                    if (RELU) v = fmaxf(v, 0.0f);
                    if (OUT_BF16)
                        ((unsigned short*)out)[(size_t)row * N + col] = f2bf(v);
                    else
                        ((float*)out)[(size_t)row * N + col] = v;
                }
            }
        }
    }
}

// ---------------------------------------------------------------------------

extern "C" void kernel_launch(void* const* d_in, const int* in_sizes, int n_in,
                              void* d_out, int out_size, void* d_ws, size_t ws_size,
                              hipStream_t stream)
{
    const float* x   = (const float*)d_in[0];
    const float* Wn0 = (const float*)d_in[1];
    const float* Ws0 = (const float*)d_in[2];
    const float* b0  = (const float*)d_in[3];
    const float* Wn1 = (const float*)d_in[4];
    const float* Ws1 = (const float*)d_in[5];
    const float* b1  = (const float*)d_in[6];
    const float* Wn2 = (const float*)d_in[7];
    const float* Ws2 = (const float*)d_in[8];
    const float* b2  = (const float*)d_in[9];
    const int* src0 = (const int*)d_in[10];
    const int* dst0 = (const int*)d_in[11];
    const int* src1 = (const int*)d_in[12];
    const int* dst1 = (const int*)d_in[13];
    const int* src2 = (const int*)d_in[14];
    const int* dst2 = (const int*)d_in[15];
    const int E0 = in_sizes[10], E1 = in_sizes[12], E2 = in_sizes[14];
    const int E_tot = E0 + E1 + E2;

    // --- workspace layout ---
    unsigned short* xb   = (unsigned short*)d_ws;             // [100000][256]
    unsigned short* mean = xb   + (size_t)NSRC  * 256;        // [50048][256]
    unsigned short* h0   = mean + (size_t)50048 * 256;        // [50048][256]
    unsigned short* h1   = h0   + (size_t)50048 * 256;        // [25088][256]
    unsigned short* Wt0  = h1   + (size_t)25088 * 256;        // [256][512]
    unsigned short* Wt1  = Wt0  + 256 * 512;
    unsigned short* Wt2  = Wt1  + 256 * 512;                  // [128][512]
    int* wptr   = (int*)(Wt2 + 128 * 512);                    // [87500]
    int* bkt    = wptr + M_TOT;                               // [87500*64]
    float* outp = (float*)d_out;

    // wptr must be zero before scatter atomics (stream-ordered).
    hipMemsetAsync(wptr, 0, (size_t)M_TOT * sizeof(int), stream);

    const int sc_b = (E_tot + 255) / 256;
    scatter_kernel<<<dim3(NPART * sc_b), dim3(256), 0, stream>>>(
        src0, dst0, src1, dst1, src2, dst2, wptr, bkt, E0, E1, E2);
    cast_prep_kernel<<<dim3(CAST_B + PREP_B), dim3(256), 0, stream>>>(
        x, xb, Wn0, Ws0, Wn1, Ws1, Wn2, Ws2, Wt0, Wt1, Wt2);

    auto run_layer = [&](const unsigned short* hin, int node_off, int M,
                         const unsigned short* Wt, const float* b,
                         void* hout, int N, bool relu, bool out_bf16) {
        // ATTRIBUTION PROBE: aggregate launched twice (idempotent).
        aggregate_mean_bf16<<<dim3((M + 3) / 4), dim3(256), 0, stream>>>(
            hin, wptr + node_off, bkt + (size_t)node_off * CAP, mean, M);
        aggregate_mean_bf16<<<dim3((M + 3) / 4), dim3(256), 0, stream>>>(
            hin, wptr + node_off, bkt + (size_t)node_off * CAP, mean, M);
        dim3 g(N / 128, (M + 127) / 128);
        if (out_bf16)
            sage_mfma<1, 1><<<g, dim3(256), 0, stream>>>(mean, hin, Wt, b, hout, M, N);
        else
            sage_mfma<0, 0><<<g, dim3(256), 0, stream>>>(mean, hin, Wt, b, hout, M, N);
    };

    run_layer(xb, 0,         M0, Wt0, b0, h0,   256, true,  true);
    run_layer(h0, NODE_OFF1, M1, Wt1, b1, h1,   256, true,  true);
    run_layer(h1, NODE_OFF2, M2, Wt2, b2, outp, 128, false, false);
}

// Round 8
// 406.098 us; speedup vs baseline: 1.1145x; 1.1145x over previous
//
#include <hip/hip_runtime.h>
#include <hip/hip_bf16.h>

// ---------------------------------------------------------------------------
// GraphSAGE 3-layer, bf16, bucket-CSR. R18 = R17 resubmitted verbatim
// (R7 bench was an infra failure — container failed twice, no counters).
//   (1) agg double-launch probe REVERTED (R16 measured agg total ~70us warm).
//   (2) sage_mfma retiled to BN = full-N (256 for L0/L1): A (mean|h) is read
//       ONCE instead of N/128=2x. R16 analysis: AI = 58 FLOP/B << 400
//       break-even -> GEMM is traffic-bound; R15's dbuf attacked the wrong
//       axis. 128x256 tile, 48KB single-buffer LDS, 4 waves, each 64x128
//       (acc 4x8). L2 keeps BN=128 (already full-N).
// Swizzle pair (rule #21) and gload_lds16 staging unchanged (verified).
// ---------------------------------------------------------------------------

typedef __attribute__((ext_vector_type(8))) short bf16x8;
typedef __attribute__((ext_vector_type(8))) unsigned short u16x8;
typedef __attribute__((ext_vector_type(4))) float floatx4;

constexpr int M0 = 50000, M1 = 25000, M2 = 12500;
constexpr int NODE_OFF1 = 50000, NODE_OFF2 = 75000, M_TOT = 87500;
constexpr int NSRC = 100000;
constexpr int NPART = 8;
constexpr int CAP = 64;     // bucket capacity per node

__device__ inline unsigned short f2bf(float f) {
    union { float f; unsigned int u; } v{f};
    unsigned int u = v.u;
    return (unsigned short)((u + 0x7FFFu + ((u >> 16) & 1u)) >> 16);  // RNE
}
__device__ inline float bf2f(unsigned short h) {
    union { unsigned int u; float f; } v{(unsigned int)h << 16};
    return v.f;
}

__device__ inline void gload_lds16(const void* g, void* l) {
    __builtin_amdgcn_global_load_lds(
        (const __attribute__((address_space(1))) unsigned int*)g,
        (__attribute__((address_space(3))) unsigned int*)l, 16, 0, 0);
}

// ---- cast + weight prep ---------------------------------------------------
constexpr int CAST_B = 25000;           // NSRC*256/4 / 256
constexpr int PREP_B = 640;

__global__ __launch_bounds__(256) void cast_prep_kernel(
    const float* __restrict__ x, unsigned short* __restrict__ xb,
    const float* __restrict__ Wn0, const float* __restrict__ Ws0,
    const float* __restrict__ Wn1, const float* __restrict__ Ws1,
    const float* __restrict__ Wn2, const float* __restrict__ Ws2,
    unsigned short* __restrict__ Wt0, unsigned short* __restrict__ Wt1,
    unsigned short* __restrict__ Wt2)
{
    const int blk = blockIdx.x;
    if (blk < CAST_B) {
        long i = (long)blk * 256 + threadIdx.x;     // over NSRC*64 ushort4's
        float4 v = reinterpret_cast<const float4*>(x)[i];
        ushort4 o{f2bf(v.x), f2bf(v.y), f2bf(v.z), f2bf(v.w)};
        reinterpret_cast<ushort4*>(xb)[i] = o;
    } else {
        int b = blk - CAST_B;
        const float* Wn; const float* Ws; unsigned short* Wt; int N; int base;
        if (b < 256)      { Wn = Wn0; Ws = Ws0; Wt = Wt0; N = 256; base = 0; }
        else if (b < 512) { Wn = Wn1; Ws = Ws1; Wt = Wt1; N = 256; base = 256; }
        else              { Wn = Wn2; Ws = Ws2; Wt = Wt2; N = 128; base = 512; }
        int idx = (b - base) * 256 + threadIdx.x;   // over N*256, k fastest
        int n = idx >> 8, k = idx & 255;
        if (n >= N) return;
        Wt[(size_t)n * 512 + k]       = f2bf(Wn[(size_t)k * N + n]);
        Wt[(size_t)n * 512 + 256 + k] = f2bf(Ws[(size_t)k * N + n]);
    }
}

// ---- bucket scatter -------------------------------------------------------
__global__ __launch_bounds__(256) void scatter_kernel(
    const int* __restrict__ src0, const int* __restrict__ dst0,
    const int* __restrict__ src1, const int* __restrict__ dst1,
    const int* __restrict__ src2, const int* __restrict__ dst2,
    int* __restrict__ wptr, int* __restrict__ bkt,
    int E0, int E1, int E2)
{
    const int b = blockIdx.x;
    const int part = b & (NPART - 1);
    const int i = (b >> 3) * 256 + threadIdx.x;
    const int lo = (int)(((long)M_TOT * part) / NPART);
    const int hi = (int)(((long)M_TOT * (part + 1)) / NPART);
    int node, j;
    const int* sp;
    if (i < E0) {
        node = dst0[i]; sp = src0; j = i;
    } else if (i < E0 + E1) {
        j = i - E0; node = NODE_OFF1 + dst1[j]; sp = src1;
    } else if (i < E0 + E1 + E2) {
        j = i - E0 - E1; node = NODE_OFF2 + dst2[j]; sp = src2;
    } else return;
    if (node >= lo && node < hi) {
        int s = sp[j];
        int p = atomicAdd(&wptr[node], 1);
        if (p < CAP) bkt[(size_t)node * CAP + p] = s;
    }
}

// ---- Aggregation: 1 wave/node, 2 rows per iteration (16B/lane) ------------

__global__ __launch_bounds__(256) void aggregate_mean_bf16(
    const unsigned short* __restrict__ h, const int* __restrict__ wptr,
    const int* __restrict__ bkt, unsigned short* __restrict__ mean, int M)
{
    int gid = blockIdx.x * 256 + threadIdx.x;
    int node = gid >> 6;
    int lane = gid & 63;
    if (node >= M) return;
    int cnt = min(wptr[node], CAP);
    int sidx = bkt[(size_t)node * CAP + lane];      // whole list, 1 coalesced read
    const int half = lane >> 5;
    const int lq = lane & 31;
    const unsigned short* hb = h + lq * 8;
    float acc[8] = {};
    int pf = cnt >> 1;          // full pairs: both halves valid, no predication
    int p = 0;
    for (; p + 4 <= pf; p += 4) {
#pragma unroll
        for (int j = 0; j < 4; ++j) {
            int s = __shfl(sidx, 2 * (p + j) + half);
            u16x8 row = *(const u16x8*)(hb + (size_t)s * 256);
#pragma unroll
            for (int k = 0; k < 8; ++k) acc[k] += bf2f(row[k]);
        }
    }
    for (; p < pf; ++p) {
        int s = __shfl(sidx, 2 * p + half);
        u16x8 row = *(const u16x8*)(hb + (size_t)s * 256);
#pragma unroll
        for (int k = 0; k < 8; ++k) acc[k] += bf2f(row[k]);
    }
    if (cnt & 1) {              // odd tail: even half only
        int s = __shfl(sidx, cnt - 1);
        if (half == 0) {
            u16x8 row = *(const u16x8*)(hb + (size_t)s * 256);
#pragma unroll
            for (int k = 0; k < 8; ++k) acc[k] += bf2f(row[k]);
        }
    }
#pragma unroll
    for (int k = 0; k < 8; ++k) acc[k] += __shfl_xor(acc[k], 32);
    if (half == 0) {
        float invd = 1.0f / (float)max(cnt, 1);
        u16x8 o;
#pragma unroll
        for (int k = 0; k < 8; ++k) o[k] = f2bf(acc[k] * invd);
        *(u16x8*)(mean + (size_t)node * 256 + lq * 8) = o;
    }
}

// ---- Fused-K MFMA GEMM, full-N tile ---------------------------------------
// C[m][n] = sum_{k<512} Acat[m][k] * Wt[n][k],  Acat = [mean | h] (K-concat).
// Tile 128 x BN (BN = full N), BK=64, 4 waves (2x2), each wave 64 x BN/2.
// A is read ONCE (was N/128 times). LDS single-buffer: sA 16KB + sB BN/4 KB.
// Staging: gload_lds16, linear LDS, XOR-swizzle pair (rule #21):
//   source byte ^= ((row&7)<<4) within each 128B K-slice; ds_read same XOR.

template <int RELU, int OUT_BF16, int BN>
__global__ __launch_bounds__(256) void sage_mfma(
    const unsigned short* __restrict__ A1,  // mean  [>=ceil128(M)][256]
    const unsigned short* __restrict__ A2,  // hsrc  [>=ceil128(M)][256]
    const unsigned short* __restrict__ Wt,  // [N][512]
    const float* __restrict__ bias,
    void* __restrict__ out, int M, int N)
{
    constexpr int NJ = BN / 32;              // 16-col fragments per wave
    constexpr int GTOT = (128 + BN) / 8;     // 1024B staging groups per step
    constexpr int GPW = GTOT / 4;            // groups per wave

    __shared__ unsigned short sA[128 * 64];  // 16 KB
    __shared__ unsigned short sB[BN * 64];   // BN/4 KB

    const int tid = threadIdx.x;
    const int bm = blockIdx.y * 128;
    const int bn = blockIdx.x * BN;
    const int wid = tid >> 6, lane = tid & 63;
    const int wm = (wid >> 1) * 64;
    const int wn = (wid & 1) * (BN / 2);
    const int quad = lane >> 4, l16 = lane & 15;

    // staging: group g covers LDS bytes [g*1024, +1024); lane l -> row
    // (g or g-16)*8 + (l>>3), byte (l&7)*16 in the 128B row, source
    // pre-swizzled by ^((row&7)<<4).
    const int srow = lane >> 3;
    const int swz = ((lane & 7) * 16) ^ (srow << 4);
    const int rswz = (l16 & 7) << 4;

    floatx4 acc[4][NJ] = {};

    for (int t = 0; t < 8; ++t) {
        const int k0 = t * 64;
        const unsigned short* Ab = (k0 < 256) ? A1 : A2;
        const int ak = k0 & 255;
        __syncthreads();                 // all waves done reading prev tile
#pragma unroll
        for (int u = 0; u < GPW; ++u) {
            const int g = u * 4 + wid;   // 0..GTOT-1, waves interleaved
            if (g < 16) {                // A groups: rows g*8+srow
                const int r = g * 8 + srow;
                gload_lds16((const char*)(Ab + (size_t)(bm + r) * 256 + ak) + swz,
                            (char*)sA + g * 1024);
            } else {                     // B groups: rows (g-16)*8+srow
                const int gb = g - 16;
                const int r = gb * 8 + srow;
                gload_lds16((const char*)(Wt + (size_t)(bn + r) * 512 + k0) + swz,
                            (char*)sB + gb * 1024);
            }
        }
        __syncthreads();                 // compiler drains vmcnt before barrier
#pragma unroll
        for (int ks = 0; ks < 64; ks += 32) {
            bf16x8 af[4], bfr[NJ];
#pragma unroll
            for (int i = 0; i < 4; ++i) {
                const int row = wm + i * 16 + l16;
                af[i] = *(const bf16x8*)((const char*)sA + row * 128 +
                                         ((ks * 2 + quad * 16) ^ rswz));
            }
#pragma unroll
            for (int j = 0; j < NJ; ++j) {
                const int row = wn + j * 16 + l16;
                bfr[j] = *(const bf16x8*)((const char*)sB + row * 128 +
                                          ((ks * 2 + quad * 16) ^ rswz));
            }
#pragma unroll
            for (int i = 0; i < 4; ++i)
#pragma unroll
                for (int j = 0; j < NJ; ++j)
                    acc[i][j] = __builtin_amdgcn_mfma_f32_16x16x32_bf16(
                        af[i], bfr[j], acc[i][j], 0, 0, 0);
        }
    }

    // epilogue: C row = quad*4 + reg, col = l16 (verified m89/m91)
#pragma unroll
    for (int j = 0; j < NJ; ++j) {
        int col = bn + wn + j * 16 + l16;
        float bcol = bias[col];
#pragma unroll
        for (int i = 0; i < 4; ++i) {
#pragma unroll
            for (int r = 0; r < 4; ++r) {
                int row = bm + wm + i * 16 + quad * 4 + r;
                if (row < M) {
                    float v = acc[i][j][r] + bcol;
                    if (RELU) v = fmaxf(v, 0.0f);
                    if (OUT_BF16)
                        ((unsigned short*)out)[(size_t)row * N + col] = f2bf(v);
                    else
                        ((float*)out)[(size_t)row * N + col] = v;
                }
            }
        }
    }
}

// ---------------------------------------------------------------------------

extern "C" void kernel_launch(void* const* d_in, const int* in_sizes, int n_in,
                              void* d_out, int out_size, void* d_ws, size_t ws_size,
                              hipStream_t stream)
{
    const float* x   = (const float*)d_in[0];
    const float* Wn0 = (const float*)d_in[1];
    const float* Ws0 = (const float*)d_in[2];
    const float* b0  = (const float*)d_in[3];
    const float* Wn1 = (const float*)d_in[4];
    const float* Ws1 = (const float*)d_in[5];
    const float* b1  = (const float*)d_in[6];
    const float* Wn2 = (const float*)d_in[7];
    const float* Ws2 = (const float*)d_in[8];
    const float* b2  = (const float*)d_in[9];
    const int* src0 = (const int*)d_in[10];
    const int* dst0 = (const int*)d_in[11];
    const int* src1 = (const int*)d_in[12];
    const int* dst1 = (const int*)d_in[13];
    const int* src2 = (const int*)d_in[14];
    const int* dst2 = (const int*)d_in[15];
    const int E0 = in_sizes[10], E1 = in_sizes[12], E2 = in_sizes[14];
    const int E_tot = E0 + E1 + E2;

    // --- workspace layout ---
    unsigned short* xb   = (unsigned short*)d_ws;             // [100000][256]
    unsigned short* mean = xb   + (size_t)NSRC  * 256;        // [50048][256]
    unsigned short* h0   = mean + (size_t)50048 * 256;        // [50048][256]
    unsigned short* h1   = h0   + (size_t)50048 * 256;        // [25088][256]
    unsigned short* Wt0  = h1   + (size_t)25088 * 256;        // [256][512]
    unsigned short* Wt1  = Wt0  + 256 * 512;
    unsigned short* Wt2  = Wt1  + 256 * 512;                  // [128][512]
    int* wptr   = (int*)(Wt2 + 128 * 512);                    // [87500]
    int* bkt    = wptr + M_TOT;                               // [87500*64]
    float* outp = (float*)d_out;

    // wptr must be zero before scatter atomics (stream-ordered).
    hipMemsetAsync(wptr, 0, (size_t)M_TOT * sizeof(int), stream);

    const int sc_b = (E_tot + 255) / 256;
    scatter_kernel<<<dim3(NPART * sc_b), dim3(256), 0, stream>>>(
        src0, dst0, src1, dst1, src2, dst2, wptr, bkt, E0, E1, E2);
    cast_prep_kernel<<<dim3(CAST_B + PREP_B), dim3(256), 0, stream>>>(
        x, xb, Wn0, Ws0, Wn1, Ws1, Wn2, Ws2, Wt0, Wt1, Wt2);

    // layer 0: M=50000, N=256, relu, bf16 out
    aggregate_mean_bf16<<<dim3((M0 + 3) / 4), dim3(256), 0, stream>>>(
        xb, wptr, bkt, mean, M0);
    sage_mfma<1, 1, 256><<<dim3(1, (M0 + 127) / 128), dim3(256), 0, stream>>>(
        mean, xb, Wt0, b0, h0, M0, 256);

    // layer 1: M=25000, N=256, relu, bf16 out
    aggregate_mean_bf16<<<dim3((M1 + 3) / 4), dim3(256), 0, stream>>>(
        h0, wptr + NODE_OFF1, bkt + (size_t)NODE_OFF1 * CAP, mean, M1);
    sage_mfma<1, 1, 256><<<dim3(1, (M1 + 127) / 128), dim3(256), 0, stream>>>(
        mean, h0, Wt1, b1, h1, M1, 256);

    // layer 2: M=12500, N=128, no relu, f32 out
    aggregate_mean_bf16<<<dim3((M2 + 3) / 4), dim3(256), 0, stream>>>(
        h1, wptr + NODE_OFF2, bkt + (size_t)NODE_OFF2 * CAP, mean, M2);
    sage_mfma<0, 0, 128><<<dim3(1, (M2 + 127) / 128), dim3(256), 0, stream>>>(
        mean, h1, Wt2, b2, outp, M2, 128);
}

// Round 9
// 373.664 us; speedup vs baseline: 1.2112x; 1.0868x over previous
//
#include <hip/hip_runtime.h>
#include <hip/hip_bf16.h>

// ---------------------------------------------------------------------------
// GraphSAGE 3-layer, bf16, bucket-CSR. R19: sage_mfma = 128x128 tile (R13/R14
// geometry reverted — full-N R18 regressed: halved TLP at same per-work time)
// with TRUE T4 counted-vmcnt 2-buffer pipeline:
//   prologue: stage(buf0,t0), stage(buf1,t1)
//   step t:   s_waitcnt vmcnt(8)   // t's 8 loads landed, t+1's 8 in flight
//             s_barrier; compute(buf t&1); s_barrier; stage(buf t&1, t+2)
// R18 post-mortem: FETCH halved, dur unchanged 67us -> not traffic-bound;
// per-byte step time invariant across R13/R18 (5100cyc/32KB vs 9900/48KB)
// -> serialized drain-per-step is the limiter. R15 drained vmcnt(0) per step
// (the documented m218 trap: dbuf-with-drain0 == no dbuf). Latency now paid
// once in prologue, not 8x.
// ---------------------------------------------------------------------------

typedef __attribute__((ext_vector_type(8))) short bf16x8;
typedef __attribute__((ext_vector_type(8))) unsigned short u16x8;
typedef __attribute__((ext_vector_type(4))) float floatx4;

constexpr int M0 = 50000, M1 = 25000, M2 = 12500;
constexpr int NODE_OFF1 = 50000, NODE_OFF2 = 75000, M_TOT = 87500;
constexpr int NSRC = 100000;
constexpr int NPART = 8;
constexpr int CAP = 64;     // bucket capacity per node

__device__ inline unsigned short f2bf(float f) {
    union { float f; unsigned int u; } v{f};
    unsigned int u = v.u;
    return (unsigned short)((u + 0x7FFFu + ((u >> 16) & 1u)) >> 16);  // RNE
}
__device__ inline float bf2f(unsigned short h) {
    union { unsigned int u; float f; } v{(unsigned int)h << 16};
    return v.f;
}

__device__ inline void gload_lds16(const void* g, void* l) {
    __builtin_amdgcn_global_load_lds(
        (const __attribute__((address_space(1))) unsigned int*)g,
        (__attribute__((address_space(3))) unsigned int*)l, 16, 0, 0);
}

// ---- cast + weight prep ---------------------------------------------------
constexpr int CAST_B = 25000;           // NSRC*256/4 / 256
constexpr int PREP_B = 640;

__global__ __launch_bounds__(256) void cast_prep_kernel(
    const float* __restrict__ x, unsigned short* __restrict__ xb,
    const float* __restrict__ Wn0, const float* __restrict__ Ws0,
    const float* __restrict__ Wn1, const float* __restrict__ Ws1,
    const float* __restrict__ Wn2, const float* __restrict__ Ws2,
    unsigned short* __restrict__ Wt0, unsigned short* __restrict__ Wt1,
    unsigned short* __restrict__ Wt2)
{
    const int blk = blockIdx.x;
    if (blk < CAST_B) {
        long i = (long)blk * 256 + threadIdx.x;     // over NSRC*64 ushort4's
        float4 v = reinterpret_cast<const float4*>(x)[i];
        ushort4 o{f2bf(v.x), f2bf(v.y), f2bf(v.z), f2bf(v.w)};
        reinterpret_cast<ushort4*>(xb)[i] = o;
    } else {
        int b = blk - CAST_B;
        const float* Wn; const float* Ws; unsigned short* Wt; int N; int base;
        if (b < 256)      { Wn = Wn0; Ws = Ws0; Wt = Wt0; N = 256; base = 0; }
        else if (b < 512) { Wn = Wn1; Ws = Ws1; Wt = Wt1; N = 256; base = 256; }
        else              { Wn = Wn2; Ws = Ws2; Wt = Wt2; N = 128; base = 512; }
        int idx = (b - base) * 256 + threadIdx.x;   // over N*256, k fastest
        int n = idx >> 8, k = idx & 255;
        if (n >= N) return;
        Wt[(size_t)n * 512 + k]       = f2bf(Wn[(size_t)k * N + n]);
        Wt[(size_t)n * 512 + 256 + k] = f2bf(Ws[(size_t)k * N + n]);
    }
}

// ---- bucket scatter -------------------------------------------------------
__global__ __launch_bounds__(256) void scatter_kernel(
    const int* __restrict__ src0, const int* __restrict__ dst0,
    const int* __restrict__ src1, const int* __restrict__ dst1,
    const int* __restrict__ src2, const int* __restrict__ dst2,
    int* __restrict__ wptr, int* __restrict__ bkt,
    int E0, int E1, int E2)
{
    const int b = blockIdx.x;
    const int part = b & (NPART - 1);
    const int i = (b >> 3) * 256 + threadIdx.x;
    const int lo = (int)(((long)M_TOT * part) / NPART);
    const int hi = (int)(((long)M_TOT * (part + 1)) / NPART);
    int node, j;
    const int* sp;
    if (i < E0) {
        node = dst0[i]; sp = src0; j = i;
    } else if (i < E0 + E1) {
        j = i - E0; node = NODE_OFF1 + dst1[j]; sp = src1;
    } else if (i < E0 + E1 + E2) {
        j = i - E0 - E1; node = NODE_OFF2 + dst2[j]; sp = src2;
    } else return;
    if (node >= lo && node < hi) {
        int s = sp[j];
        int p = atomicAdd(&wptr[node], 1);
        if (p < CAP) bkt[(size_t)node * CAP + p] = s;
    }
}

// ---- Aggregation: 1 wave/node, 2 rows per iteration (16B/lane) ------------

__global__ __launch_bounds__(256) void aggregate_mean_bf16(
    const unsigned short* __restrict__ h, const int* __restrict__ wptr,
    const int* __restrict__ bkt, unsigned short* __restrict__ mean, int M)
{
    int gid = blockIdx.x * 256 + threadIdx.x;
    int node = gid >> 6;
    int lane = gid & 63;
    if (node >= M) return;
    int cnt = min(wptr[node], CAP);
    int sidx = bkt[(size_t)node * CAP + lane];      // whole list, 1 coalesced read
    const int half = lane >> 5;
    const int lq = lane & 31;
    const unsigned short* hb = h + lq * 8;
    float acc[8] = {};
    int pf = cnt >> 1;          // full pairs: both halves valid, no predication
    int p = 0;
    for (; p + 4 <= pf; p += 4) {
#pragma unroll
        for (int j = 0; j < 4; ++j) {
            int s = __shfl(sidx, 2 * (p + j) + half);
            u16x8 row = *(const u16x8*)(hb + (size_t)s * 256);
#pragma unroll
            for (int k = 0; k < 8; ++k) acc[k] += bf2f(row[k]);
        }
    }
    for (; p < pf; ++p) {
        int s = __shfl(sidx, 2 * p + half);
        u16x8 row = *(const u16x8*)(hb + (size_t)s * 256);
#pragma unroll
        for (int k = 0; k < 8; ++k) acc[k] += bf2f(row[k]);
    }
    if (cnt & 1) {              // odd tail: even half only
        int s = __shfl(sidx, cnt - 1);
        if (half == 0) {
            u16x8 row = *(const u16x8*)(hb + (size_t)s * 256);
#pragma unroll
            for (int k = 0; k < 8; ++k) acc[k] += bf2f(row[k]);
        }
    }
#pragma unroll
    for (int k = 0; k < 8; ++k) acc[k] += __shfl_xor(acc[k], 32);
    if (half == 0) {
        float invd = 1.0f / (float)max(cnt, 1);
        u16x8 o;
#pragma unroll
        for (int k = 0; k < 8; ++k) o[k] = f2bf(acc[k] * invd);
        *(u16x8*)(mean + (size_t)node * 256 + lq * 8) = o;
    }
}

// ---- Fused-K MFMA GEMM, counted-vmcnt 2-buffer pipeline -------------------
// C[m][n] = sum_{k<512} Acat[m][k] * Wt[n][k],  Acat = [mean | h] (K-concat).
// 128x128 tile, BK=64, 4 waves, 64x64/wave as 4x4 mfma_f32_16x16x32_bf16.
// Staging: gload_lds16, 8 loads/wave/step; LDS linear, XOR-swizzle pair
// (rule #21, verified R14+): source byte ^= ((row&7)<<4) in 128B K-slice,
// ds_read same XOR. Pipeline: 2 buffers, s_waitcnt vmcnt(8) per step
// (never 0 in the loop) — tile t+1's loads stay in flight across compute.

template <int RELU, int OUT_BF16>
__global__ __launch_bounds__(256) void sage_mfma(
    const unsigned short* __restrict__ A1,  // mean  [>=ceil128(M)][256]
    const unsigned short* __restrict__ A2,  // hsrc  [>=ceil128(M)][256]
    const unsigned short* __restrict__ Wt,  // [N][512]
    const float* __restrict__ bias,
    void* __restrict__ out, int M, int N)
{
    __shared__ unsigned short sA[2][128 * 64];   // 2 x 16 KB
    __shared__ unsigned short sB[2][128 * 64];   // 2 x 16 KB

    const int tid = threadIdx.x;
    const int bm = blockIdx.y * 128;
    const int bn = blockIdx.x * 128;
    const int wid = tid >> 6, lane = tid & 63;
    const int wm = (wid >> 1) * 64;
    const int wn = (wid & 1) * 64;
    const int quad = lane >> 4, l16 = lane & 15;

    const int srow = lane >> 3;
    const int swz = ((lane & 7) * 16) ^ (srow << 4);
    const int rswz = (l16 & 7) << 4;

    floatx4 acc[4][4] = {};

    auto stage = [&](int buf, int t) {
        const int k0 = t * 64;
        const unsigned short* Ab = (k0 < 256) ? A1 : A2;
        const int ak = k0 & 255;
#pragma unroll
        for (int u = 0; u < 4; ++u) {
            const int g = wid * 4 + u;            // 0..15, 8 rows each
            const int r = g * 8 + srow;
            gload_lds16((const char*)(Ab + (size_t)(bm + r) * 256 + ak) + swz,
                        (char*)(sA[buf]) + g * 1024);
            gload_lds16((const char*)(Wt + (size_t)(bn + r) * 512 + k0) + swz,
                        (char*)(sB[buf]) + g * 1024);
        }
    };

    auto compute = [&](int buf) {
#pragma unroll
        for (int ks = 0; ks < 64; ks += 32) {
            bf16x8 af[4], bfr[4];
#pragma unroll
            for (int i = 0; i < 4; ++i) {
                const int row = wm + i * 16 + l16;
                af[i] = *(const bf16x8*)((const char*)(sA[buf]) + row * 128 +
                                         ((ks * 2 + quad * 16) ^ rswz));
            }
#pragma unroll
            for (int j = 0; j < 4; ++j) {
                const int row = wn + j * 16 + l16;
                bfr[j] = *(const bf16x8*)((const char*)(sB[buf]) + row * 128 +
                                          ((ks * 2 + quad * 16) ^ rswz));
            }
#pragma unroll
            for (int i = 0; i < 4; ++i)
#pragma unroll
                for (int j = 0; j < 4; ++j)
                    acc[i][j] = __builtin_amdgcn_mfma_f32_16x16x32_bf16(
                        af[i], bfr[j], acc[i][j], 0, 0, 0);
        }
    };

    // prologue: two tiles in flight
    stage(0, 0);
    stage(1, 1);

#pragma unroll
    for (int t = 0; t < 8; ++t) {
        if (t < 7) {
            // tile t's 8 loads done; tile t+1's 8 may remain outstanding
            asm volatile("s_waitcnt vmcnt(8)" ::: "memory");
        } else {
            asm volatile("s_waitcnt vmcnt(0)" ::: "memory");
        }
        __builtin_amdgcn_s_barrier();        // all waves' t-loads landed
        __builtin_amdgcn_sched_barrier(0);   // keep ds_reads below the sync
        compute(t & 1);
        if (t < 7) {
            __builtin_amdgcn_s_barrier();    // all waves done reading buf t&1
            if (t + 2 < 8) stage(t & 1, t + 2);
        }
    }

    // epilogue: C row = quad*4 + reg, col = l16 (verified m89/m91)
#pragma unroll
    for (int j = 0; j < 4; ++j) {
        int col = bn + wn + j * 16 + l16;
        float bcol = bias[col];
#pragma unroll
        for (int i = 0; i < 4; ++i) {
#pragma unroll
            for (int r = 0; r < 4; ++r) {
                int row = bm + wm + i * 16 + quad * 4 + r;
                if (row < M) {
                    float v = acc[i][j][r] + bcol;
                    if (RELU) v = fmaxf(v, 0.0f);
                    if (OUT_BF16)
                        ((unsigned short*)out)[(size_t)row * N + col] = f2bf(v);
                    else
                        ((float*)out)[(size_t)row * N + col] = v;
                }
            }
        }
    }
}

// ---------------------------------------------------------------------------

extern "C" void kernel_launch(void* const* d_in, const int* in_sizes, int n_in,
                              void* d_out, int out_size, void* d_ws, size_t ws_size,
                              hipStream_t stream)
{
    const float* x   = (const float*)d_in[0];
    const float* Wn0 = (const float*)d_in[1];
    const float* Ws0 = (const float*)d_in[2];
    const float* b0  = (const float*)d_in[3];
    const float* Wn1 = (const float*)d_in[4];
    const float* Ws1 = (const float*)d_in[5];
    const float* b1  = (const float*)d_in[6];
    const float* Wn2 = (const float*)d_in[7];
    const float* Ws2 = (const float*)d_in[8];
    const float* b2  = (const float*)d_in[9];
    const int* src0 = (const int*)d_in[10];
    const int* dst0 = (const int*)d_in[11];
    const int* src1 = (const int*)d_in[12];
    const int* dst1 = (const int*)d_in[13];
    const int* src2 = (const int*)d_in[14];
    const int* dst2 = (const int*)d_in[15];
    const int E0 = in_sizes[10], E1 = in_sizes[12], E2 = in_sizes[14];
    const int E_tot = E0 + E1 + E2;

    // --- workspace layout ---
    unsigned short* xb   = (unsigned short*)d_ws;             // [100000][256]
    unsigned short* mean = xb   + (size_t)NSRC  * 256;        // [50048][256]
    unsigned short* h0   = mean + (size_t)50048 * 256;        // [50048][256]
    unsigned short* h1   = h0   + (size_t)50048 * 256;        // [25088][256]
    unsigned short* Wt0  = h1   + (size_t)25088 * 256;        // [256][512]
    unsigned short* Wt1  = Wt0  + 256 * 512;
    unsigned short* Wt2  = Wt1  + 256 * 512;                  // [128][512]
    int* wptr   = (int*)(Wt2 + 128 * 512);                    // [87500]
    int* bkt    = wptr + M_TOT;                               // [87500*64]
    float* outp = (float*)d_out;

    // wptr must be zero before scatter atomics (stream-ordered).
    hipMemsetAsync(wptr, 0, (size_t)M_TOT * sizeof(int), stream);

    const int sc_b = (E_tot + 255) / 256;
    scatter_kernel<<<dim3(NPART * sc_b), dim3(256), 0, stream>>>(
        src0, dst0, src1, dst1, src2, dst2, wptr, bkt, E0, E1, E2);
    cast_prep_kernel<<<dim3(CAST_B + PREP_B), dim3(256), 0, stream>>>(
        x, xb, Wn0, Ws0, Wn1, Ws1, Wn2, Ws2, Wt0, Wt1, Wt2);

    auto run_layer = [&](const unsigned short* hin, int node_off, int M,
                         const unsigned short* Wt, const float* b,
                         void* hout, int N, bool relu, bool out_bf16) {
        aggregate_mean_bf16<<<dim3((M + 3) / 4), dim3(256), 0, stream>>>(
            hin, wptr + node_off, bkt + (size_t)node_off * CAP, mean, M);
        dim3 g(N / 128, (M + 127) / 128);
        if (out_bf16)
            sage_mfma<1, 1><<<g, dim3(256), 0, stream>>>(mean, hin, Wt, b, hout, M, N);
        else
            sage_mfma<0, 0><<<g, dim3(256), 0, stream>>>(mean, hin, Wt, b, hout, M, N);
    };

    run_layer(xb, 0,         M0, Wt0, b0, h0,   256, true,  true);
    run_layer(h0, NODE_OFF1, M1, Wt1, b1, h1,   256, true,  true);
    run_layer(h1, NODE_OFF2, M2, Wt2, b2, outp, 128, false, false);
}